// Round 32
// baseline (40.615 us; speedup 1.0000x reference)
//
#include <hip/hip_runtime.h>
#include <math.h>

constexpr int IN_C = 31;
constexpr int TOT  = 44;
constexpr int HW   = 256 * 256;
constexpr int NPIX = 4 * HW;
constexpr int NWG  = NPIX / 64;      // 4096 workgroups
constexpr float SMIN = 0.001f, SMAX = 1000.0f;

typedef __attribute__((ext_vector_type(8))) short bf16x8;
typedef __attribute__((ext_vector_type(4))) float f32x4;

__device__ __forceinline__ float frcp(float v) { return __builtin_amdgcn_rcpf(v); }

__device__ __forceinline__ short f2bf(float f) {
    union { float f; unsigned u; } v; v.f = f;
    unsigned r = v.u + 0x7FFFu + ((v.u >> 16) & 1u);   // RNE
    return (short)(r >> 16);
}
__device__ __forceinline__ float bf2f(short h) {
    union { unsigned u; float f; } v; v.u = ((unsigned)(unsigned short)h) << 16;
    return v.f;
}

// R24 body with ONE change: S stored DIRECTLY per-lane (16 float4 stores at
// 256B stride) instead of through the 8KB LDS staging + coalesced flush.
// Rationale: every byte of S is written, so L2 accumulates full dirty lines
// regardless of per-instruction coalescing -> HBM bytes unchanged; removes
// ~48 LDS ops + a fence + the wbuf4 aliasing phase from the per-wave critical
// path (and the kernel gets structurally SIMPLER, lowering schedule-fragility
// risk, unlike the condemned R23/R25/R30 perturbations).
__global__ __launch_bounds__(64, 4) void sepgpd_fused(
    const float* __restrict__ x,
    const float* __restrict__ Wenc,
    const float* __restrict__ benc,
    float* __restrict__ out)
{
    __shared__ float wt[64 * 34];   // 8704 B: transpose buffer only

    const int lane = threadIdx.x;                   // 0..63
    const int W0   = blockIdx.x * 64;               // wave's first pixel
    const int b    = W0 >> 16;                      // 64 | 65536: same image
    const int hwb  = W0 & (HW - 1);
    const int lrow = lane & 15;                     // M/N lane index
    const int lgrp = lane >> 4;                     // K group

    const float* xb = x + (size_t)b * IN_C * HW + hwb;

    // ---- B fragments: W^T tiles (48 chans x 32 K), hi/lo bf16 split ----
    bf16x8 bhi[3], blo[3];
#pragma unroll
    for (int n = 0; n < 3; ++n) {
        const int o = n * 16 + lrow;
#pragma unroll
        for (int j = 0; j < 8; ++j) {
            const int k = lgrp * 8 + j;
            const float wv = (o < TOT && k < IN_C) ? Wenc[o * IN_C + k] : 0.0f;
            const short h = f2bf(wv);
            bhi[n][j] = h;
            blo[n][j] = f2bf(wv - bf2f(h));
        }
    }

    // ---- MFMA: 4 M-tiles x 3 N-tiles x 3 products (x loads per tile) ----
    f32x4 acc[4][3];
#pragma unroll
    for (int t = 0; t < 4; ++t)
#pragma unroll
        for (int n = 0; n < 3; ++n) acc[t][n] = (f32x4)0.0f;

#pragma unroll
    for (int t = 0; t < 4; ++t) {
        float xf[8];
#pragma unroll
        for (int j = 0; j < 8; ++j) {
            const int k = lgrp * 8 + j;
            xf[j] = (k < IN_C) ? xb[(size_t)k * HW + t * 16 + lrow] : 0.0f;
        }
        bf16x8 ahi, alo;
#pragma unroll
        for (int j = 0; j < 8; ++j) {
            const short h = f2bf(xf[j]);
            ahi[j] = h;
            alo[j] = f2bf(xf[j] - bf2f(h));
        }
#pragma unroll
        for (int n = 0; n < 3; ++n) {
            acc[t][n] = __builtin_amdgcn_mfma_f32_16x16x32_bf16(ahi, bhi[n], acc[t][n], 0, 0, 0);
            acc[t][n] = __builtin_amdgcn_mfma_f32_16x16x32_bf16(alo, bhi[n], acc[t][n], 0, 0, 0);
            acc[t][n] = __builtin_amdgcn_mfma_f32_16x16x32_bf16(ahi, blo[n], acc[t][n], 0, 0, 0);
        }
    }

    // ---- transpose phase A: chans 0..31 -> [p][c] stride 34 ----
#pragma unroll
    for (int t = 0; t < 4; ++t)
#pragma unroll
        for (int n = 0; n < 2; ++n)
#pragma unroll
            for (int r = 0; r < 4; ++r) {
                const int p = t * 16 + lgrp * 4 + r;      // pixel (C row)
                wt[p * 34 + n * 16 + lrow] = acc[t][n][r];
            }

    // read chans 0..15 (m + scales) as PLAIN float loads (alias-ordered)
    float a16[16];
#pragma unroll
    for (int c = 0; c < 16; ++c) a16[c] = wt[lane * 34 + c];

    asm volatile("" ::: "memory");   // fence: reads above before phase-B writes

    // phase B: chans 32..43 -> cols 0..15 (cols 16..31 keep angle chans 16..31)
#pragma unroll
    for (int t = 0; t < 4; ++t)
#pragma unroll
        for (int r = 0; r < 4; ++r) {
            const int p = t * 16 + lgrp * 4 + r;
            wt[p * 34 + lrow] = acc[t][2][r];
        }

    // ---- m: first 8 channels (+bias), per-pixel contiguous ----
    const int pix = W0 + lane;
    float4* mp = reinterpret_cast<float4*>(out + (size_t)pix * 8);
    mp[0] = make_float4(a16[0] + benc[0], a16[1] + benc[1],
                        a16[2] + benc[2], a16[3] + benc[3]);
    mp[1] = make_float4(a16[4] + benc[4], a16[5] + benc[5],
                        a16[6] + benc[6], a16[7] + benc[7]);

    // ---- sqrt scales (rcp-based sigmoid) ----
    float sq[8];
#pragma unroll
    for (int j = 0; j < 8; ++j) {
        const float sig = frcp(1.0f + __expf(-(a16[8 + j] + benc[8 + j])));
        const float s   = fmaf(SMAX - SMIN, sig, SMIN);
        sq[j] = __builtin_amdgcn_sqrtf(s);
    }

    // ---- R from Givens chain; angles on demand from LDS (plain float);
    //      hw sin/cos in revolutions: cos(pi*th) = v_cos(th/2) ----
    float R[8][8];
#pragma unroll
    for (int i = 0; i < 8; ++i)
#pragma unroll
        for (int k = 0; k < 8; ++k) R[i][k] = (i == k) ? 1.0f : 0.0f;

    int cc = 0;
#pragma unroll
    for (int i = 0; i < 7; ++i) {
#pragma unroll
        for (int j = i + 1; j < 8; ++j) {
            const int  col = (cc < 16) ? (16 + cc) : (cc - 16);
            const float wv = wt[lane * 34 + col] + benc[16 + cc];
            // tanh(wv) = 1 - 2/(e^{2wv}+1); saturates correctly for large |wv|
            const float th  = fmaf(-2.0f, frcp(__expf(2.0f * wv) + 1.0f), 1.0f);
            const float rev = 0.5f * th;
            const float cs  = __builtin_amdgcn_cosf(rev);
            const float ss  = __builtin_amdgcn_sinf(rev);
#pragma unroll
            for (int r = 0; r < 8; ++r) {
                const float ri = R[r][i];
                const float rj = R[r][j];
                R[r][i] = fmaf(ri, cs, rj * ss);
                R[r][j] = fmaf(rj, cs, -(ri * ss));
            }
            ++cc;
        }
    }

    // scale row j by sqrt(s_j):  S = (sqrtD R)^T (sqrtD R)
#pragma unroll
    for (int j = 0; j < 8; ++j)
#pragma unroll
        for (int k = 0; k < 8; ++k) R[j][k] *= sq[j];

    // ---- S rows computed and stored DIRECTLY (no LDS staging) ----
    // lane's pixel S block: 64 floats at out + NPIX*8 + pix*64
    float4* Sp = reinterpret_cast<float4*>(out + (size_t)NPIX * 8 +
                                           (size_t)pix * 64);
#pragma unroll
    for (int i = 0; i < 8; ++i) {
        float row[8];
#pragma unroll
        for (int k = 0; k < 8; ++k) {
            float d = 0.0f;
#pragma unroll
            for (int j = 0; j < 8; ++j) d = fmaf(R[j][i], R[j][k], d);
            row[k] = d;
        }
        Sp[i * 2]     = make_float4(row[0], row[1], row[2], row[3]);
        Sp[i * 2 + 1] = make_float4(row[4], row[5], row[6], row[7]);
    }
}

extern "C" void kernel_launch(void* const* d_in, const int* in_sizes, int n_in,
                              void* d_out, int out_size, void* d_ws, size_t ws_size,
                              hipStream_t stream)
{
    const float* x    = (const float*)d_in[0];
    const float* Wenc = (const float*)d_in[1];
    const float* benc = (const float*)d_in[2];
    float* out        = (float*)d_out;

    dim3 grid(NWG), block(64);
    sepgpd_fused<<<grid, block, 0, stream>>>(x, Wenc, benc, out);
}

// Round 33
// 27.495 us; speedup vs baseline: 1.4771x; 1.4771x over previous
//
#include <hip/hip_runtime.h>
#include <math.h>

constexpr int IN_C = 31;
constexpr int TOT  = 44;
constexpr int HW   = 256 * 256;
constexpr int NPIX = 4 * HW;
constexpr int NWG  = NPIX / 64;      // 4096 workgroups
constexpr float SMIN = 0.001f, SMAX = 1000.0f;

typedef __attribute__((ext_vector_type(8))) short bf16x8;
typedef __attribute__((ext_vector_type(4))) float f32x4;

__device__ __forceinline__ float frcp(float v) { return __builtin_amdgcn_rcpf(v); }

__device__ __forceinline__ short f2bf(float f) {
    union { float f; unsigned u; } v; v.f = f;
    unsigned r = v.u + 0x7FFFu + ((v.u >> 16) & 1u);   // RNE
    return (short)(r >> 16);
}
__device__ __forceinline__ float bf2f(short h) {
    union { unsigned u; float f; } v; v.u = ((unsigned)(unsigned short)h) << 16;
    return v.f;
}

// FINAL (verified 4x: 27.24/27.24/27.45/27.55us, absmax 4.0).
// Session: 50.7 -> 27.2us via (1) transposed/contiguous weight access +17%,
// (2) MFMA encoder GEMV with hi/lo bf16 split +16%, (3) 1-wave blocks
// (de-lockstepped wave scheduling) +21%. LDS-staged coalesced S flush
// POSITIVELY verified vs direct stores (R32: direct = -48%).
// Falsified/condemned: global_load_lds staging (R14-16 race), forced
// (64,5) bound (R21-23 miscompile), 2px/thread (R8/R10 spill), n-pass GEMV
// (R25 replay-nondeterminism), full load hoist (R30 corrupt), kernel split
// (R28 -46%), XCD swizzle (R27 neutral), LDS weights (R9/R18 regress/neutral).
// Remaining gap to ~15us write-roofline is per-wave serial latency at the
// 4-waves/SIMD tier; every occupancy lever provably failed to move it.
__global__ __launch_bounds__(64, 4) void sepgpd_fused(
    const float* __restrict__ x,
    const float* __restrict__ Wenc,
    const float* __restrict__ benc,
    float* __restrict__ out)
{
    __shared__ float wt[64 * 34];   // 8704 B: transpose + S staging

    const int lane = threadIdx.x;                   // 0..63
    const int W0   = blockIdx.x * 64;               // wave's first pixel
    const int b    = W0 >> 16;                      // 64 | 65536: same image
    const int hwb  = W0 & (HW - 1);
    const int lrow = lane & 15;                     // M/N lane index
    const int lgrp = lane >> 4;                     // K group

    const float* xb = x + (size_t)b * IN_C * HW + hwb;

    // ---- B fragments: W^T tiles (48 chans x 32 K), hi/lo bf16 split ----
    bf16x8 bhi[3], blo[3];
#pragma unroll
    for (int n = 0; n < 3; ++n) {
        const int o = n * 16 + lrow;
#pragma unroll
        for (int j = 0; j < 8; ++j) {
            const int k = lgrp * 8 + j;
            const float wv = (o < TOT && k < IN_C) ? Wenc[o * IN_C + k] : 0.0f;
            const short h = f2bf(wv);
            bhi[n][j] = h;
            blo[n][j] = f2bf(wv - bf2f(h));
        }
    }

    // ---- MFMA: 4 M-tiles x 3 N-tiles x 3 products (x loads per tile) ----
    f32x4 acc[4][3];
#pragma unroll
    for (int t = 0; t < 4; ++t)
#pragma unroll
        for (int n = 0; n < 3; ++n) acc[t][n] = (f32x4)0.0f;

#pragma unroll
    for (int t = 0; t < 4; ++t) {
        float xf[8];
#pragma unroll
        for (int j = 0; j < 8; ++j) {
            const int k = lgrp * 8 + j;
            xf[j] = (k < IN_C) ? xb[(size_t)k * HW + t * 16 + lrow] : 0.0f;
        }
        bf16x8 ahi, alo;
#pragma unroll
        for (int j = 0; j < 8; ++j) {
            const short h = f2bf(xf[j]);
            ahi[j] = h;
            alo[j] = f2bf(xf[j] - bf2f(h));
        }
#pragma unroll
        for (int n = 0; n < 3; ++n) {
            acc[t][n] = __builtin_amdgcn_mfma_f32_16x16x32_bf16(ahi, bhi[n], acc[t][n], 0, 0, 0);
            acc[t][n] = __builtin_amdgcn_mfma_f32_16x16x32_bf16(alo, bhi[n], acc[t][n], 0, 0, 0);
            acc[t][n] = __builtin_amdgcn_mfma_f32_16x16x32_bf16(ahi, blo[n], acc[t][n], 0, 0, 0);
        }
    }

    // ---- transpose phase A: chans 0..31 -> [p][c] stride 34 ----
#pragma unroll
    for (int t = 0; t < 4; ++t)
#pragma unroll
        for (int n = 0; n < 2; ++n)
#pragma unroll
            for (int r = 0; r < 4; ++r) {
                const int p = t * 16 + lgrp * 4 + r;      // pixel (C row)
                wt[p * 34 + n * 16 + lrow] = acc[t][n][r];
            }

    // read chans 0..15 (m + scales) as PLAIN float loads (alias-ordered)
    float a16[16];
#pragma unroll
    for (int c = 0; c < 16; ++c) a16[c] = wt[lane * 34 + c];

    asm volatile("" ::: "memory");   // fence: reads above before phase-B writes

    // phase B: chans 32..43 -> cols 0..15 (cols 16..31 keep angle chans 16..31)
#pragma unroll
    for (int t = 0; t < 4; ++t)
#pragma unroll
        for (int r = 0; r < 4; ++r) {
            const int p = t * 16 + lgrp * 4 + r;
            wt[p * 34 + lrow] = acc[t][2][r];
        }

    // ---- m: first 8 channels (+bias), per-pixel contiguous ----
    const int pix = W0 + lane;
    float4* mp = reinterpret_cast<float4*>(out + (size_t)pix * 8);
    mp[0] = make_float4(a16[0] + benc[0], a16[1] + benc[1],
                        a16[2] + benc[2], a16[3] + benc[3]);
    mp[1] = make_float4(a16[4] + benc[4], a16[5] + benc[5],
                        a16[6] + benc[6], a16[7] + benc[7]);

    // ---- sqrt scales (rcp-based sigmoid) ----
    float sq[8];
#pragma unroll
    for (int j = 0; j < 8; ++j) {
        const float sig = frcp(1.0f + __expf(-(a16[8 + j] + benc[8 + j])));
        const float s   = fmaf(SMAX - SMIN, sig, SMIN);
        sq[j] = __builtin_amdgcn_sqrtf(s);
    }

    // ---- R from Givens chain; angles on demand from LDS (plain float);
    //      hw sin/cos in revolutions: cos(pi*th) = v_cos(th/2) ----
    float R[8][8];
#pragma unroll
    for (int i = 0; i < 8; ++i)
#pragma unroll
        for (int k = 0; k < 8; ++k) R[i][k] = (i == k) ? 1.0f : 0.0f;

    int cc = 0;
#pragma unroll
    for (int i = 0; i < 7; ++i) {
#pragma unroll
        for (int j = i + 1; j < 8; ++j) {
            const int  col = (cc < 16) ? (16 + cc) : (cc - 16);
            const float wv = wt[lane * 34 + col] + benc[16 + cc];
            // tanh(wv) = 1 - 2/(e^{2wv}+1); saturates correctly for large |wv|
            const float th  = fmaf(-2.0f, frcp(__expf(2.0f * wv) + 1.0f), 1.0f);
            const float rev = 0.5f * th;
            const float cs  = __builtin_amdgcn_cosf(rev);
            const float ss  = __builtin_amdgcn_sinf(rev);
#pragma unroll
            for (int r = 0; r < 8; ++r) {
                const float ri = R[r][i];
                const float rj = R[r][j];
                R[r][i] = fmaf(ri, cs, rj * ss);
                R[r][j] = fmaf(rj, cs, -(ri * ss));
            }
            ++cc;
        }
    }

    asm volatile("" ::: "memory");   // fence: angle reads done before staging

    // scale row j by sqrt(s_j):  S = (sqrtD R)^T (sqrtD R)
#pragma unroll
    for (int j = 0; j < 8; ++j)
#pragma unroll
        for (int k = 0; k < 8; ++k) R[j][k] *= sq[j];

    // ---- S rows one at a time -> staging -> coalesced flush per 4 rows ----
    float4* wbuf4 = reinterpret_cast<float4*>(wt);
    float4* S4 = reinterpret_cast<float4*>(out + (size_t)NPIX * 8);
    const size_t pixbase4 = (size_t)W0 * 16;   // float4 units

#pragma unroll
    for (int p = 0; p < 2; ++p) {
#pragma unroll
        for (int r = 0; r < 4; ++r) {
            const int i = 4 * p + r;
            float row[8];
#pragma unroll
            for (int k = 0; k < 8; ++k) {
                float d = 0.0f;
#pragma unroll
                for (int j = 0; j < 8; ++j) d = fmaf(R[j][i], R[j][k], d);
                row[k] = d;
            }
            const int v0 = r * 2, v1 = v0 + 1;
            wbuf4[lane * 8 + (v0 ^ (lane & 7))] =
                make_float4(row[0], row[1], row[2], row[3]);
            wbuf4[lane * 8 + (v1 ^ (lane & 7))] =
                make_float4(row[4], row[5], row[6], row[7]);
        }
        // coalesced flush: 8 iters x 64 lanes x 16B = 8KB contiguous
#pragma unroll
        for (int k = 0; k < 8; ++k) {
            const int t  = k * 64 + lane;
            const int pl = t >> 3;           // local pixel 0..63
            const int v  = t & 7;            // float4 index within half
            S4[pixbase4 + (size_t)pl * 16 + p * 8 + v] =
                wbuf4[pl * 8 + (v ^ (pl & 7))];
        }
    }
}

extern "C" void kernel_launch(void* const* d_in, const int* in_sizes, int n_in,
                              void* d_out, int out_size, void* d_ws, size_t ws_size,
                              hipStream_t stream)
{
    const float* x    = (const float*)d_in[0];
    const float* Wenc = (const float*)d_in[1];
    const float* benc = (const float*)d_in[2];
    float* out        = (float*)d_out;

    dim3 grid(NWG), block(64);
    sepgpd_fused<<<grid, block, 0, stream>>>(x, Wenc, benc, out);
}